// Round 7
// baseline (735.567 us; speedup 1.0000x reference)
//
#include <hip/hip_runtime.h>
#include <stdint.h>

#define B_ 256
#define L_ 1024
#define T_ 64

typedef float f4v __attribute__((ext_vector_type(4)));

__device__ __forceinline__ float rfl(float x) {
    return __int_as_float(__builtin_amdgcn_readfirstlane(__float_as_int(x)));
}
__device__ __forceinline__ float rlane(float x, int j) {
    return __int_as_float(__builtin_amdgcn_readlane(__float_as_int(x), j));
}

// global -> LDS direct DMA, 16B per lane. LDS dest = base + lane*16 (linear);
// global src is per-lane. AS casts via uintptr (generic LDS ptr low 32 = offset).
typedef __attribute__((address_space(3))) uint32_t lds_u32;
typedef __attribute__((address_space(1))) uint32_t glb_u32;
__device__ __forceinline__ void gload16(const void* g, void* l) {
    __builtin_amdgcn_global_load_lds((const glb_u32*)(uintptr_t)g,
                                     (lds_u32*)(uintptr_t)l, 16, 0, 0);
}

#define X64(M) M(0) M(1) M(2) M(3) M(4) M(5) M(6) M(7) M(8) M(9) M(10) M(11) \
  M(12) M(13) M(14) M(15) M(16) M(17) M(18) M(19) M(20) M(21) M(22) M(23) \
  M(24) M(25) M(26) M(27) M(28) M(29) M(30) M(31) M(32) M(33) M(34) M(35) \
  M(36) M(37) M(38) M(39) M(40) M(41) M(42) M(43) M(44) M(45) M(46) M(47) \
  M(48) M(49) M(50) M(51) M(52) M(53) M(54) M(55) M(56) M(57) M(58) M(59) \
  M(60) M(61) M(62) M(63)

#define XR0(M) M(0) M(8) M(16) M(24) M(32) M(40) M(48) M(56)
#define XR1(M) M(1) M(9) M(17) M(25) M(33) M(41) M(49) M(57)
#define XR2(M) M(2) M(10) M(18) M(26) M(34) M(42) M(50) M(58)
#define XR3(M) M(3) M(11) M(19) M(27) M(35) M(43) M(51) M(59)
#define XR4(M) M(4) M(12) M(20) M(28) M(36) M(44) M(52) M(60)
#define XR5(M) M(5) M(13) M(21) M(29) M(37) M(45) M(53) M(61)
#define XR6(M) M(6) M(14) M(22) M(30) M(38) M(46) M(54) M(62)
#define XR7(M) M(7) M(15) M(23) M(31) M(39) M(47) M(55) M(63)

#define DE(n) float e##n;
#define LEF(n) e##n = __expf(trans[(n) * T_ + lane]);
#define LEB(n) e##n = __expf(trans[lane * T_ + (n)]);
#define D0(n) a0 = fmaf(rlane(dsrc, n), e##n, a0);
#define D1(n) a1 = fmaf(rlane(dsrc, n), e##n, a1);
#define D2(n) a2 = fmaf(rlane(dsrc, n), e##n, a2);
#define D3(n) a3 = fmaf(rlane(dsrc, n), e##n, a3);
#define D4(n) a4 = fmaf(rlane(dsrc, n), e##n, a4);
#define D5(n) a5 = fmaf(rlane(dsrc, n), e##n, a5);
#define D6(n) a6 = fmaf(rlane(dsrc, n), e##n, a6);
#define D7(n) a7 = fmaf(rlane(dsrc, n), e##n, a7);
#define DOT_ALL() XR0(D0) XR1(D1) XR2(D2) XR3(D3) XR4(D4) XR5(D5) XR6(D6) XR7(D7)

// One wave per chain. blockIdx<256: fwd batch b; else bwd batch b-256.
// Lane = tag k. E=exp(trans) in 64 named scalars. State u in exp domain,
// u[0]==1, log-state = c + log(u). Dot = 64x (v_readlane + v_fmac).
// em: LDS-staged 16-step double buffer via global_load_lds, 1 ds_read/step.
// mask: fully LDS-staged. The ONLY vm waits: vmcnt(0) in prologue and
// vmcnt(16) at chunk boundaries (16 = the outstanding alpha/beta stores,
// which are thus never waited on). No s_barrier anywhere (1 wave/block).
__global__ __launch_bounds__(64, 1)
void crf_scan(const float* __restrict__ em, const float* __restrict__ start_t,
              const float* __restrict__ end_t, const float* __restrict__ trans,
              const int* __restrict__ mask, float* __restrict__ alpha,
              float* __restrict__ beta, float* __restrict__ zbuf)
{
    const int lane = threadIdx.x;
    const int cb = blockIdx.x;
    const bool fwd = cb < B_;
    const int b = fwd ? cb : cb - B_;

    __shared__ float em_lds[32 * T_];   // 8KB: 2 chunks x 16 rows x 64 floats
    __shared__ int   mk_lds[L_];        // 4KB: whole mask row

    const float* emb = em + (size_t)b * (L_ * T_);
    const int* mb = mask + (size_t)b * L_;
    const size_t stride = (size_t)B_ * T_;

    // ---- staging helpers ----
#define STAGE(ch) { \
    const char* gs = (const char*)emb + (size_t)(ch) * 4096; \
    char* ls = (char*)em_lds + ((ch) & 1) * 4096; \
    gload16(gs + lane * 16, ls); \
    gload16(gs + 1024 + lane * 16, ls + 1024); \
    gload16(gs + 2048 + lane * 16, ls + 2048); \
    gload16(gs + 3072 + lane * 16, ls + 3072); }

    // prologue staging: whole mask + first two em chunks
    {
        const char* gm = (const char*)mb;
        char* lm = (char*)mk_lds;
        gload16(gm + lane * 16, lm);
        gload16(gm + 1024 + lane * 16, lm + 1024);
        gload16(gm + 2048 + lane * 16, lm + 2048);
        gload16(gm + 3072 + lane * 16, lm + 3072);
    }
    if (fwd) { STAGE(0) STAGE(1) } else { STAGE(63) STAGE(62) }

    // E in 64 named scalars
    X64(DE)
    if (fwd) { X64(LEF) } else { X64(LEB) }

    asm volatile("s_waitcnt vmcnt(0)" ::: "memory");

    if (fwd) {
        float em0 = em_lds[lane];
        float st0 = em0 + start_t[lane];
        float c = rfl(st0);
        float u = __expf(st0 - c);                 // u[0] == 1
        float av = st0;
        float* ap = alpha + (size_t)b * T_ + lane;
        *ap = av;
        ap += stride;

#pragma unroll 1
        for (int t = 1; t < L_; ++t) {
            if ((t & 15) == 0) {                   // chunk boundary
                asm volatile("s_waitcnt vmcnt(16)" ::: "memory");
                int ch = t >> 4;
                if (ch < 63) STAGE(ch + 1)
            }
            float emv = em_lds[(t & 31) * T_ + lane];  // ds_read, hidden
            int mvv = mk_lds[t];
            float dsrc = u;
            float a0=0.f,a1=0.f,a2=0.f,a3=0.f,a4=0.f,a5=0.f,a6=0.f,a7=0.f;
            DOT_ALL()
            float dot = ((a0+a1)+(a2+a3))+((a4+a5)+(a6+a7));
            float f = __expf(emv);
            float ld = __logf(dot);
            float u00 = rfl(dot) * rfl(f);
            float r = __builtin_amdgcn_rcpf(u00);
            float cand = (dot * f) * r;
            bool mk = (mvv != 0);
            av = mk ? ((c + ld) + emv) : av;        // alpha_t = c + log(dot) + em
            c  = mk ? (c + rfl(ld) + rfl(emv)) : c;
            u  = mk ? cand : u;
            *ap = av;
            ap += stride;
        }
        // z_b = c + log(sum_k u_k * exp(end_k))
        float v = u * __expf(end_t[lane]);
        for (int off = 32; off; off >>= 1) v += __shfl_xor(v, off);
        if (lane == 0) zbuf[b] = c + __logf(v);
    } else {
        // state v = exp(beta + em_i - g), v[0]==1 after each unmasked step
        float bv = end_t[lane];
        float* bp = beta + ((size_t)(L_ - 1) * B_ + b) * T_ + lane;
        *bp = bv;
        bp -= stride;
        float emQ = em_lds[31 * T_ + lane];        // row 1023 -> slot 31
        float g = rfl(bv + emQ);
        float v = __expf((bv + emQ) - g);
        float fold = __expf(emQ);

#pragma unroll 1
        for (int i = L_ - 1; i >= 1; --i) {
            if ((i & 15) == 0) {                   // chunk boundary
                asm volatile("s_waitcnt vmcnt(16)" ::: "memory");
                int ch = i >> 4;
                if (ch >= 2) STAGE(ch - 2)
            }
            float emv = em_lds[((i - 1) & 31) * T_ + lane];  // em_{i-1}
            int mvv = mk_lds[i];
            float dsrc = v;
            float a0=0.f,a1=0.f,a2=0.f,a3=0.f,a4=0.f,a5=0.f,a6=0.f,a7=0.f;
            DOT_ALL()
            float dot = ((a0+a1)+(a2+a3))+((a4+a5)+(a6+a7));
            float f = __expf(emv);                 // f_{i-1}
            float ld = __logf(dot);
            float u00 = rfl(dot) * rfl(f);
            float r = __builtin_amdgcn_rcpf(u00);
            float vu = (dot * f) * r;              // unmasked next v
            float vm = (v * f) * __builtin_amdgcn_rcpf(fold);  // masked next v
            bool mk = (mvv != 0);
            bv = mk ? (g + ld) : bv;               // beta_{i-1} = g + log(dot)
            g  = mk ? (g + rfl(ld) + rfl(emv)) : g;
            v  = mk ? vu : vm;
            fold = f;
            *bp = bv;
            bp -= stride;
        }
    }
#undef STAGE
}

// out = exp(alpha + beta - z[b]); beta already resides in d_out.
__global__ __launch_bounds__(256)
void crf_finalize(const float* __restrict__ alpha,
                  const float* __restrict__ zbuf,
                  float* __restrict__ out)
{
    const f4v* a4 = (const f4v*)alpha;
    f4v* o4 = (f4v*)out;
    size_t base = (size_t)blockIdx.x * 256 + threadIdx.x;
    const size_t step = (size_t)2048 * 256;
#pragma unroll
    for (int r = 0; r < 8; ++r) {
        size_t i4 = base + (size_t)r * step;
        int b = (int)((i4 >> 4) & (B_ - 1));       // 16 float4 per (t,b) row
        float z = zbuf[b];
        f4v a = a4[i4];
        f4v bb = o4[i4];
        f4v o;
        o.x = __expf(a.x + bb.x - z);
        o.y = __expf(a.y + bb.y - z);
        o.z = __expf(a.z + bb.z - z);
        o.w = __expf(a.w + bb.w - z);
        __builtin_nontemporal_store(o, &o4[i4]);
    }
}

extern "C" void kernel_launch(void* const* d_in, const int* in_sizes, int n_in,
                              void* d_out, int out_size, void* d_ws, size_t ws_size,
                              hipStream_t stream) {
    const float* em = (const float*)d_in[0];
    const float* st = (const float*)d_in[1];
    const float* en = (const float*)d_in[2];
    const float* tr = (const float*)d_in[3];
    const int*   mk = (const int*)d_in[4];
    float* out   = (float*)d_out;
    float* alpha = (float*)d_ws;
    float* zbuf  = alpha + (size_t)L_ * B_ * T_;

    crf_scan<<<2 * B_, T_, 0, stream>>>(em, st, en, tr, mk, alpha, out, zbuf);
    crf_finalize<<<2048, 256, 0, stream>>>(alpha, zbuf, out);
}